// Round 14
// baseline (88.234 us; speedup 1.0000x reference)
//
#include <hip/hip_runtime.h>
#include <hip/hip_bf16.h>

#define BB     64
#define NF4    200000        // NTOT / 4
#define CHUNKS 3125          // NF4 / 64
#define NP     128
#define NH1    256
#define NH2    128
#define NC     32
#define EPSV   1e-5f
#define ROWPAD 1040          // 65 float4 per row: bank-stagger across rows
#define SLOT   (8 * ROWPAD)  // 8 rows per octet slot

typedef float fx4 __attribute__((ext_vector_type(4)));

#define AS_G __attribute__((address_space(1)))
#define AS_L __attribute__((address_space(3)))

__device__ __forceinline__ float dot4(fx4 a, fx4 b) {
    return fmaf(a[0], b[0], fmaf(a[1], b[1], fmaf(a[2], b[2], a[3] * b[3])));
}

__device__ __forceinline__ int bitrev3(int l) {
    return ((l & 1) << 2) | (l & 2) | ((l & 4) >> 2);
}

template <int C, int M>
__device__ __forceinline__ void red_step(float* v, int lane) {
    const bool hi = (lane & M) != 0;
    #pragma unroll
    for (int j = 0; j < C / 2; ++j) {
        float mine  = hi ? v[j + C / 2] : v[j];
        float other = hi ? v[j]         : v[j + C / 2];
        v[j] = mine + __shfl_xor(other, M);
    }
}

// ---------------------------------------------------------------------------
// Scatter-reduce: WX[b, idx[n]] += x[b,n] * w[n]     (idx sorted)
// One wave per 64-quad chunk. TRANSPOSED consume: lane l owns row (l&7)
// (one batch per octet) and columns (l>>3)+8j, accumulating a REGISTER-
// LOCAL partial. The 8-octet steady loop contains ONLY: counted vmcnt(8),
// 8 asm ds_read_b128, 32 FMA, 8 DMA issues — zero shuffles, zero ballots,
// zero atomics. One 7-shuffle reduce + ONE 64-lane atomic per wave at the
// end. w/idx staged once into a separate LDS region (no per-lane global
// vector loads -> vmcnt queue is pure DMA, counted waits exact).
// ---------------------------------------------------------------------------
__global__ __launch_bounds__(64) void k_scatter(
    const float* __restrict__ x, const float* __restrict__ w,
    const int* __restrict__ idx, float* __restrict__ WX)
{
    __shared__ char lds[2 * SLOT + 2048];   // 2 x-slots + w(1KB) + p(1KB)
    const int lane = threadIdx.x;           // 0..63
    const int ch   = blockIdx.x;            // 0..3124
    const int n4   = ch * 64 + lane;

    const fx4* __restrict__ x4 = reinterpret_cast<const fx4*>(x);
    const fx4* __restrict__ w4 = reinterpret_cast<const fx4*>(w);
    const int4* __restrict__ p4 = reinterpret_cast<const int4*>(idx);

    // Chunk pathway endpoints via uniform (scalar) loads.
    const int  pLo = idx[ch * 256];
    const int  pHi = idx[ch * 256 + 255];
    const bool uniform = (pLo == pHi);

    char* const wbuf = lds + 2 * SLOT;        // 1KB linear
    char* const pbuf = lds + 2 * SLOT + 1024; // 1KB linear

    // Stage w/p for this chunk (2 DMA), drain, pre-read TRANSPOSED masks.
    __builtin_amdgcn_global_load_lds((const AS_G float*)(w4 + n4),
                                     (AS_L float*)wbuf, 16, 0, 0);
    __builtin_amdgcn_global_load_lds((const AS_G float*)(p4 + n4),
                                     (AS_L float*)pbuf, 16, 0, 0);
    asm volatile("s_waitcnt vmcnt(0)" ::: "memory");

    fx4 wLo[8], wHi[8];
    #pragma unroll
    for (int j = 0; j < 8; ++j) {
        const int c = (lane >> 3) + 8 * j;    // this lane's j-th column
        const fx4  wj = *reinterpret_cast<const fx4*>(wbuf + c * 16);
        const int4 pj = *reinterpret_cast<const int4*>(pbuf + c * 16);
        wLo[j][0] = (pj.x == pLo) ? wj[0] : 0.f;
        wLo[j][1] = (pj.y == pLo) ? wj[1] : 0.f;
        wLo[j][2] = (pj.z == pLo) ? wj[2] : 0.f;
        wLo[j][3] = (pj.w == pLo) ? wj[3] : 0.f;
        if (!uniform) {
            wHi[j][0] = (pj.x == pHi) ? wj[0] : 0.f;
            wHi[j][1] = (pj.y == pHi) ? wj[1] : 0.f;
            wHi[j][2] = (pj.z == pHi) ? wj[2] : 0.f;
            wHi[j][3] = (pj.w == pHi) ? wj[3] : 0.f;
        }
    }

    auto dma = [&](int o) {                   // stage octet o into slot o&1
        char* const sb = lds + (o & 1) * SLOT;
        #pragma unroll
        for (int i = 0; i < 8; ++i) {
            const float* gp = (const float*)(x4 + ((size_t)(o * 8 + i) * NF4 + n4));
            __builtin_amdgcn_global_load_lds((const AS_G float*)gp,
                                             (AS_L float*)(sb + i * ROWPAD),
                                             16, 0, 0);
        }
    };

    dma(0); dma(1);                           // 16 loads in flight

    float acc[8], accH[8];
    #pragma unroll
    for (int o = 0; o < 8; ++o) {
        if (o < 7) asm volatile("s_waitcnt vmcnt(8)" ::: "memory");
        else       asm volatile("s_waitcnt vmcnt(0)" ::: "memory");

        char* const sb = lds + (o & 1) * SLOT;
        fx4 xr[8];
        #pragma unroll
        for (int j = 0; j < 8; ++j) {         // transposed asm consume
            const unsigned laddr = (unsigned)(size_t)(AS_L char*)
                (sb + (lane & 7) * ROWPAD + (((lane >> 3) + 8 * j) * 16));
            asm volatile("ds_read_b128 %0, %1" : "=v"(xr[j]) : "v"(laddr));
        }
        asm volatile("s_waitcnt lgkmcnt(0)" ::: "memory");
        __builtin_amdgcn_sched_barrier(0);    // rule #18

        float t[8];
        #pragma unroll
        for (int j = 0; j < 8; ++j)
            t[j] = dot4(xr[j], wLo[j]);
        acc[o] = ((t[0] + t[1]) + (t[2] + t[3])) + ((t[4] + t[5]) + (t[6] + t[7]));
        if (!uniform) {
            float th[8];
            #pragma unroll
            for (int j = 0; j < 8; ++j)
                th[j] = dot4(xr[j], wHi[j]);
            accH[o] = ((th[0] + th[1]) + (th[2] + th[3])) + ((th[4] + th[5]) + (th[6] + th[7]));
        }

        __builtin_amdgcn_sched_barrier(0);
        if (o < 6) dma(o + 2);                // refill slot just consumed
        __builtin_amdgcn_sched_barrier(0);
    }

    // Once per wave: 7 shuffles -> one value per lane -> ONE 64-lane atomic.
    const int batch = bitrev3(lane >> 3) * 8 + (lane & 7);
    red_step<8, 8>(acc, lane);
    red_step<4, 16>(acc, lane);
    red_step<2, 32>(acc, lane);
    atomicAdd(&WX[batch * NP + pLo], acc[0]);
    if (!uniform) {
        red_step<8, 8>(accH, lane);
        red_step<4, 16>(accH, lane);
        red_step<2, 32>(accH, lane);
        atomicAdd(&WX[batch * NP + pHi], accH[0]);
    }
}

// ---------------------------------------------------------------------------
// Zero WX (replaces hipMemsetAsync; PMC-visible).
// ---------------------------------------------------------------------------
__global__ void k_zero(float* __restrict__ WX)
{
    const int i = blockIdx.x * 256 + threadIdx.x;
    if (i < BB * NP) WX[i] = 0.f;
}

__device__ __forceinline__ float bn_shfl(float a, float gj, float bj)
{
    float s = a, q = a * a;
    #pragma unroll
    for (int off = 32; off > 0; off >>= 1) {
        s += __shfl_xor(s, off);
        q += __shfl_xor(q, off);
    }
    const float m   = s * (1.f / BB);
    const float var = q * (1.f / BB) - m * m;
    return (a - m) * rsqrtf(var + EPSV) * gj + bj;
}

// ---------------------------------------------------------------------------
// BN0+gate (redundant per block, parallel) + fc1 + ReLU + BN1.
// ---------------------------------------------------------------------------
__global__ __launch_bounds__(256) void k_fc1z(
    const float* __restrict__ WX,   const float* __restrict__ co_w,
    const float* __restrict__ bn0g, const float* __restrict__ bn0b,
    const float* __restrict__ W1,   const float* __restrict__ b1,
    const float* __restrict__ bn1g, const float* __restrict__ bn1b,
    float* __restrict__ Zout, float* __restrict__ h1t)
{
    __shared__ float Zl[NP * 65];    // pad 65: conflict-free write & read
    const int tid  = threadIdx.x;
    const int wv   = tid >> 6;
    const int lane = tid & 63;       // == batch in fc1 stage
    const int blk  = blockIdx.x;

    if (tid < NP) {
        const int p = tid;
        float sum = 0.f, sq = 0.f;
        #pragma unroll 8
        for (int b = 0; b < BB; ++b) {
            const float r = fmaxf(WX[b * NP + p], 0.f);
            sum += r; sq += r * r;
        }
        const float m   = sum * (1.f / BB);
        const float var = sq * (1.f / BB) - m * m;
        const float sc  = rsqrtf(var + EPSV) * bn0g[p];
        const float bt  = bn0b[p];
        const float sig = 1.f / (1.f + expf(-co_w[p]));
        #pragma unroll 8
        for (int b = 0; b < BB; ++b) {
            const float r = fmaxf(WX[b * NP + p], 0.f);
            const float z = ((r - m) * sc + bt) * sig;
            Zl[p * 65 + b] = z;
            if (blk == 0) Zout[b * NP + p] = z;
        }
    }
    __syncthreads();

    const int j = blk * 4 + wv;      // 0..255
    float acc = b1[j];
    #pragma unroll 8
    for (int k = 0; k < NP; ++k)
        acc = fmaf(Zl[k * 65 + lane], W1[k * NH1 + j], acc);
    h1t[j * BB + lane] = bn_shfl(fmaxf(acc, 0.f), bn1g[j], bn1b[j]);
}

// ---------------------------------------------------------------------------
// fc2 + ReLU + BN2 from TRANSPOSED input [K][BB]. One block per column j.
// ---------------------------------------------------------------------------
template <int K, int NOUT>
__global__ void k_fc_bn_t(const float* __restrict__ in_t,  // [K][BB]
                          const float* __restrict__ W,     // [K, NOUT]
                          const float* __restrict__ bias,
                          const float* __restrict__ g,
                          const float* __restrict__ beta,
                          float* __restrict__ out_t)       // [NOUT][BB]
{
    const int j = blockIdx.x;
    const int b = threadIdx.x;  // 0..63
    float acc = bias[j];
    #pragma unroll 8
    for (int k = 0; k < K; ++k)
        acc = fmaf(in_t[k * BB + b], W[k * NOUT + j], acc);
    out_t[j * BB + b] = bn_shfl(fmaxf(acc, 0.f), g[j], beta[j]);
}

// ---------------------------------------------------------------------------
// Final Linear + row softmax from transposed h2 [NH2][BB].
// ---------------------------------------------------------------------------
__global__ void k_head(const float* __restrict__ h2t,  // [NH2][BB]
                       const float* __restrict__ Wo,   // [NH2, NC]
                       const float* __restrict__ bo,
                       float* __restrict__ y)          // [BB, NC]
{
    const int b = blockIdx.x;
    const int c = threadIdx.x;  // 0..31
    float acc = bo[c];
    #pragma unroll 8
    for (int k = 0; k < NH2; ++k)
        acc = fmaf(h2t[k * BB + b], Wo[k * NC + c], acc);
    float mx = acc;
    #pragma unroll
    for (int off = 16; off > 0; off >>= 1)
        mx = fmaxf(mx, __shfl_xor(mx, off));
    const float e = expf(acc - mx);
    float s = e;
    #pragma unroll
    for (int off = 16; off > 0; off >>= 1)
        s += __shfl_xor(s, off);
    y[b * NC + c] = e / s;
}

// ---------------------------------------------------------------------------
extern "C" void kernel_launch(void* const* d_in, const int* in_sizes, int n_in,
                              void* d_out, int out_size, void* d_ws, size_t ws_size,
                              hipStream_t stream)
{
    const float* x    = (const float*)d_in[0];
    const float* w    = (const float*)d_in[1];
    const float* co_w = (const float*)d_in[2];
    const float* bn0g = (const float*)d_in[3];
    const float* bn0b = (const float*)d_in[4];
    const float* W1   = (const float*)d_in[5];
    const float* b1   = (const float*)d_in[6];
    const float* bn1g = (const float*)d_in[7];
    const float* bn1b = (const float*)d_in[8];
    const float* W2   = (const float*)d_in[9];
    const float* b2   = (const float*)d_in[10];
    const float* bn2g = (const float*)d_in[11];
    const float* bn2b = (const float*)d_in[12];
    const float* Wo   = (const float*)d_in[13];
    const float* bo   = (const float*)d_in[14];
    const int*   idx  = (const int*)d_in[15];

    float* out = (float*)d_out;
    float* y   = out;               // [64, 32]  (output 0)
    float* Z   = out + BB * NC;     // [64, 128] (output 1)

    float* WX  = (float*)d_ws;          // 8192 f32
    float* h1t = WX + BB * NP;          // 16384 f32  [j][b]
    float* h2t = h1t + BB * NH1;        // 8192 f32   [j][b]

    k_zero<<<32, 256, 0, stream>>>(WX);
    k_scatter<<<CHUNKS, 64, 0, stream>>>(x, w, idx, WX);
    k_fc1z<<<64, 256, 0, stream>>>(WX, co_w, bn0g, bn0b,
                                   W1, b1, bn1g, bn1b, Z, h1t);
    k_fc_bn_t<NH1, NH2><<<NH2, BB, 0, stream>>>(h1t, W2, b2, bn2g, bn2b, h2t);
    k_head<<<BB, NC, 0, stream>>>(h2t, Wo, bo, y);
}